// Round 3
// baseline (10878.728 us; speedup 1.0000x reference)
//
#include <hip/hip_runtime.h>
#include <hip/hip_bf16.h>

#define SEQ   2048
#define NBATCH 64
#define HID   512
#define KDIM  512

typedef float f32x4  __attribute__((ext_vector_type(4)));
typedef short bf16x8 __attribute__((ext_vector_type(8)));

__device__ __forceinline__ unsigned short f2bf(float f) {
  union { float f; unsigned int u; } v; v.f = f;
  unsigned int r = v.u + 0x7FFFu + ((v.u >> 16) & 1u);
  return (unsigned short)(r >> 16);
}

__device__ __forceinline__ f32x4 mfma16(bf16x8 a, bf16x8 b, f32x4 c) {
  return __builtin_amdgcn_mfma_f32_16x16x32_bf16(a, b, c, 0, 0, 0);
}

// Repack W [H=512 rows n][K=512 cols k] (row-major fp32) into MFMA-B-fragment-major bf16:
// element index = ((kf*32 + cfg)*64 + lane)*8 + e  with n = cfg*16 + (lane&15),
// k = kf*32 + (lane>>4)*8 + e.
__global__ void prep_wfrag(const float* __restrict__ W, unsigned short* __restrict__ dst) {
  int tid = blockIdx.x * blockDim.x + threadIdx.x;   // 0 .. 262143
  int e   = tid & 7;
  int l   = (tid >> 3) & 63;
  int cfg = (tid >> 9) & 31;
  int kf  = tid >> 14;
  int n = cfg * 16 + (l & 15);
  int k = kf * 32 + (l >> 4) * 8 + e;
  dst[tid] = f2bf(W[n * KDIM + k]);
}

__global__ void prep_bsum(const float* __restrict__ a, const float* __restrict__ b,
                          float* __restrict__ out) {
  int j = threadIdx.x;
  if (j < HID) out[j] = a[j] + b[j];
}

// Phase 1: xp = X * W_ih^T + (b_ih + b_hh), written TRANSPOSED into d_out:
// f32 element offset = s*32768 + bg*8192 + col*16 + b16   (s=block, bg=b>>4, b16=b&15)
// -> the scan reads 16B contiguous per lane; h(s) later overwrites slice (s,bg) in place.
__global__ __launch_bounds__(512) void rnn_xproj(
    const float* __restrict__ X,      // [131072, 512] fp32
    const uint4* __restrict__ BW,     // W_ih frag-major bf16
    const float* __restrict__ bsum,   // [512]
    float* __restrict__ out) {        // d_out as xp^T
  const int tid = threadIdx.x, w = tid >> 6, l = tid & 63;
  const int g = l >> 4, lr = l & 15;
  const int rowbase = blockIdx.x * 64 + (w >> 2) * 32;
  const int colw = (w & 3) * 128;

  f32x4 acc[2][8];
  #pragma unroll
  for (int cf = 0; cf < 8; ++cf) {
    float bv = bsum[colw + cf * 16 + lr];
    f32x4 z = {bv, bv, bv, bv};
    acc[0][cf] = z; acc[1][cf] = z;
  }

  #pragma unroll 1
  for (int kc = 0; kc < 16; ++kc) {
    const int kb = kc * 32 + g * 8;
    bf16x8 afr[2];
    #pragma unroll
    for (int ai = 0; ai < 2; ++ai) {
      const float* src = X + (size_t)(rowbase + ai * 16 + lr) * KDIM + kb;
      float4 lo = *reinterpret_cast<const float4*>(src);
      float4 hi = *reinterpret_cast<const float4*>(src + 4);
      bf16x8 a;
      a[0] = (short)f2bf(lo.x); a[1] = (short)f2bf(lo.y);
      a[2] = (short)f2bf(lo.z); a[3] = (short)f2bf(lo.w);
      a[4] = (short)f2bf(hi.x); a[5] = (short)f2bf(hi.y);
      a[6] = (short)f2bf(hi.z); a[7] = (short)f2bf(hi.w);
      afr[ai] = a;
    }
    #pragma unroll
    for (int cf = 0; cf < 8; ++cf) {
      const int cfg = (w & 3) * 8 + cf;
      uint4 braw = BW[(kc * 32 + cfg) * 64 + l];
      bf16x8 b = __builtin_bit_cast(bf16x8, braw);
      acc[0][cf] = mfma16(afr[0], b, acc[0][cf]);
      acc[1][cf] = mfma16(afr[1], b, acc[1][cf]);
    }
  }

  // xp^T write: 4 consecutive batch rows (C regs r=0..3) = one float4
  const size_t sbase = (size_t)blockIdx.x * 32768;
  #pragma unroll
  for (int ai = 0; ai < 2; ++ai) {
    const int bgl = (w >> 2) * 2 + ai;
    #pragma unroll
    for (int cf = 0; cf < 8; ++cf) {
      const int col = colw + cf * 16 + lr;
      f32x4 v = acc[ai][cf];
      *reinterpret_cast<f32x4*>(out + sbase + bgl * 8192 + col * 16 + g * 4) = v;
    }
  }
}

// Phase 2: sequential scan. 4 blocks, each owns 16 batch rows for all 2048 steps.
// LDS (163840 B):
//   [0,     131072): B-frags kf0-3, all 32 cfgs (128 x 1KB, linear)
//   [131072,147456): h buf0  (16 rows x 1024B, byte XOR ((row&7)<<4))
//   [147456,163840): h buf1
// W_hh kf4..15 in 192 VGPRs/thread (fully static indexing).
// xp read global->reg (4 x dwordx4 from xp^T); h stores + next-xp loads ride
// across the single per-step raw barrier (disjoint slices -> race-free).
__global__ __launch_bounds__(512, 2) void rnn_scan(
    const uint4* __restrict__ BW,   // W_hh frag-major bf16 (16384 frags)
    float* __restrict__ xo) {       // d_out: xp^T in, h (row-major) out
  extern __shared__ char smem[];
  const int tid = threadIdx.x, w = tid >> 6, l = tid & 63;
  const int g = l >> 4, lr = l & 15;
  const int bg = blockIdx.x;
  const int w4 = w * 4;

  // stage B kf0-3 (128KB linear)
  {
    uint4* lb = reinterpret_cast<uint4*>(smem);
    #pragma unroll
    for (int i = 0; i < 16; ++i) lb[i * 512 + tid] = BW[i * 512 + tid];
  }
  // zero h buf0
  {
    float* hz = reinterpret_cast<float*>(smem + 131072);
    #pragma unroll
    for (int i = 0; i < 8; ++i) hz[i * 512 + tid] = 0.f;
  }
  // register B-frags kf4-15 (static indices only)
  bf16x8 br[12][4];
  #pragma unroll
  for (int kf = 0; kf < 12; ++kf)
    #pragma unroll
    for (int cf = 0; cf < 4; ++cf)
      br[kf][cf] = __builtin_bit_cast(bf16x8, BW[((kf + 4) * 32 + w4 + cf) * 64 + l]);
  __syncthreads();

  // per-lane constants
  const int aswz = (lr & 7) << 4;
  const int apre = lr * 1024 + g * 16;            // + kf*64, ^aswz, + 131072 + RD
  const int col0 = w * 64 + lr;
  const int g4x  = (g & 1) << 6;
  const int xpoff = col0 * 64 + g * 16;           // bytes within (s,bg) slice; + cf*1024
  const int ovbase = g * 4 * HID + col0;          // + r*HID + cf*16 (f32 elems)
  const char* xbytes = reinterpret_cast<const char*>(xo);

  // prologue: xp(0) -> regs
  f32x4 xv[4];
  {
    const char* xb = xbytes + (size_t)bg * 131072 + xpoff;
    #pragma unroll
    for (int cf = 0; cf < 4; ++cf)
      xv[cf] = *reinterpret_cast<const f32x4*>(xb + cf * 1024);
  }

#define SCAN_STEP(S, RD, WR)                                                     \
  {                                                                              \
    const int s = (S);                                                           \
    f32x4 acc[4];                                                                \
    _Pragma("unroll")                                                            \
    for (int cf = 0; cf < 4; ++cf) { f32x4 z = {0.f,0.f,0.f,0.f}; acc[cf] = z; } \
    _Pragma("unroll")                                                            \
    for (int kf = 0; kf < 4; ++kf) {                                             \
      bf16x8 av = *reinterpret_cast<const bf16x8*>(                              \
          smem + 131072 + (RD) + ((apre + kf * 64) ^ aswz));                     \
      const char* bb = smem + ((kf * 32 + w4) << 10) + l * 16;                   \
      acc[0] = mfma16(av, *reinterpret_cast<const bf16x8*>(bb       ), acc[0]);  \
      acc[1] = mfma16(av, *reinterpret_cast<const bf16x8*>(bb + 1024), acc[1]);  \
      acc[2] = mfma16(av, *reinterpret_cast<const bf16x8*>(bb + 2048), acc[2]);  \
      acc[3] = mfma16(av, *reinterpret_cast<const bf16x8*>(bb + 3072), acc[3]);  \
    }                                                                            \
    _Pragma("unroll")                                                            \
    for (int kf = 0; kf < 12; ++kf) {                                            \
      bf16x8 av = *reinterpret_cast<const bf16x8*>(                              \
          smem + 131072 + (RD) + ((apre + (kf + 4) * 64) ^ aswz));               \
      acc[0] = mfma16(av, br[kf][0], acc[0]);                                    \
      acc[1] = mfma16(av, br[kf][1], acc[1]);                                    \
      acc[2] = mfma16(av, br[kf][2], acc[2]);                                    \
      acc[3] = mfma16(av, br[kf][3], acc[3]);                                    \
    }                                                                            \
    _Pragma("unroll")                                                            \
    for (int cf = 0; cf < 4; ++cf) {                                             \
      _Pragma("unroll")                                                          \
      for (int r = 0; r < 4; ++r) acc[cf][r] += xv[cf][r];                       \
    }                                                                            \
    { /* issue xp(s+1) early (disjoint slice; consumed next step) */             \
      const int sn = (s + 1 < SEQ) ? (s + 1) : (SEQ - 1);                        \
      const char* xb = xbytes + (size_t)sn * 131072 + (size_t)bg * 32768 + xpoff;\
      _Pragma("unroll")                                                          \
      for (int cf = 0; cf < 4; ++cf)                                             \
        xv[cf] = *reinterpret_cast<const f32x4*>(xb + cf * 1024);                \
    }                                                                            \
    float* xrow = xo + (size_t)(s * NBATCH + bg * 16) * HID;                     \
    _Pragma("unroll")                                                            \
    for (int cf = 0; cf < 4; ++cf) {                                             \
      const int col = col0 + cf * 16;                                            \
      _Pragma("unroll")                                                          \
      for (int r = 0; r < 4; ++r) {                                              \
        const float pre = acc[cf][r];                                            \
        const float hv = 1.0f - 2.0f * __builtin_amdgcn_rcpf(1.0f + __expf(2.0f * pre)); \
        xrow[ovbase + r * HID + cf * 16] = hv;                                   \
        const int ha = 131072 + (WR) +                                           \
            ((((g * 4 + r) * 1024 + col * 2) ^ g4x) ^ (r << 4));                 \
        *reinterpret_cast<unsigned short*>(smem + ha) = f2bf(hv);                \
      }                                                                          \
    }                                                                            \
    asm volatile("s_waitcnt lgkmcnt(0)" ::: "memory");                           \
    __builtin_amdgcn_s_barrier();                                                \
    __builtin_amdgcn_sched_barrier(0);                                           \
  }

  // prologue xp(0) loads target slice (0,bg): base bg*131072? No: slice base is
  // s*131072 + bg*32768; for s=0 that's bg*32768. Fix applied here:
  // (the block above used bg*131072 — correct it by re-reading)
  {
    const char* xb = xbytes + (size_t)bg * 32768 + xpoff;
    #pragma unroll
    for (int cf = 0; cf < 4; ++cf)
      xv[cf] = *reinterpret_cast<const f32x4*>(xb + cf * 1024);
  }

  #pragma unroll 1
  for (int s2 = 0; s2 < SEQ; s2 += 2) {
    SCAN_STEP(s2,     0,     16384)
    SCAN_STEP(s2 + 1, 16384, 0)
  }
#undef SCAN_STEP
}

extern "C" void kernel_launch(void* const* d_in, const int* in_sizes, int n_in,
                              void* d_out, int out_size, void* d_ws, size_t ws_size,
                              hipStream_t stream) {
  (void)in_sizes; (void)n_in; (void)out_size;
  const float* X   = (const float*)d_in[0];
  const float* Wih = (const float*)d_in[1];
  const float* Whh = (const float*)d_in[2];
  const float* bih = (const float*)d_in[3];
  const float* bhh = (const float*)d_in[4];
  float* out = (float*)d_out;

  unsigned short* wihf = (unsigned short*)d_ws;              // 512 KB
  unsigned short* whhf = wihf + 262144;                      // 512 KB
  float* bsum = (float*)(whhf + 262144);                     // 2 KB
  if (ws_size < (size_t)(2 * 524288 + 2048)) return;

  prep_wfrag<<<1024, 256, 0, stream>>>(Wih, wihf);
  prep_wfrag<<<1024, 256, 0, stream>>>(Whh, whhf);
  prep_bsum<<<1, 512, 0, stream>>>(bih, bhh, bsum);

  rnn_xproj<<<2048, 512, 0, stream>>>(X, (const uint4*)wihf, bsum, out);

  hipFuncSetAttribute(reinterpret_cast<const void*>(rnn_scan),
                      hipFuncAttributeMaxDynamicSharedMemorySize, 163840);
  rnn_scan<<<4, 512, 163840, stream>>>((const uint4*)whhf, out);
}

// Round 4
// 6107.957 us; speedup vs baseline: 1.7811x; 1.7811x over previous
//
#include <hip/hip_runtime.h>
#include <hip/hip_bf16.h>

#define SEQ   2048
#define NBATCH 64
#define HID   512
#define KDIM  512

typedef float f32x4  __attribute__((ext_vector_type(4)));
typedef short bf16x8 __attribute__((ext_vector_type(8)));

__device__ __forceinline__ unsigned short f2bf(float f) {
  union { float f; unsigned int u; } v; v.f = f;
  unsigned int r = v.u + 0x7FFFu + ((v.u >> 16) & 1u);
  return (unsigned short)(r >> 16);
}

__device__ __forceinline__ f32x4 mfma16(bf16x8 a, bf16x8 b, f32x4 c) {
  return __builtin_amdgcn_mfma_f32_16x16x32_bf16(a, b, c, 0, 0, 0);
}

// Repack W [H=512 rows n][K=512 cols k] (row-major fp32) into MFMA-fragment-major bf16:
// element index = ((kf*32 + cfg)*64 + lane)*8 + e  with n = cfg*16 + (lane&15),
// k = kf*32 + (lane>>4)*8 + e.  Used as B-frag (phase 1) and A-frag (scan).
__global__ void prep_wfrag(const float* __restrict__ W, unsigned short* __restrict__ dst) {
  int tid = blockIdx.x * blockDim.x + threadIdx.x;   // 0 .. 262143
  int e   = tid & 7;
  int l   = (tid >> 3) & 63;
  int cfg = (tid >> 9) & 31;
  int kf  = tid >> 14;
  int n = cfg * 16 + (l & 15);
  int k = kf * 32 + (l >> 4) * 8 + e;
  dst[tid] = f2bf(W[n * KDIM + k]);
}

__global__ void prep_bsum(const float* __restrict__ a, const float* __restrict__ b,
                          float* __restrict__ out) {
  int j = threadIdx.x;
  if (j < HID) out[j] = a[j] + b[j];
}

// Phase 1: xp = X * W_ih^T + (b_ih + b_hh), written to d_out in NATURAL layout
// [s*64+b][n] fp32 (the scan reads it as f32x4 per (b, n-quad)).
__global__ __launch_bounds__(512) void rnn_xproj(
    const float* __restrict__ X,      // [131072, 512] fp32
    const uint4* __restrict__ BW,     // W_ih frag-major bf16
    const float* __restrict__ bsum,   // [512]
    float* __restrict__ out) {        // [131072, 512] fp32 (xp)
  const int tid = threadIdx.x, w = tid >> 6, l = tid & 63;
  const int g = l >> 4, lr = l & 15;
  const int rowbase = blockIdx.x * 64 + (w >> 2) * 32;
  const int colw = (w & 3) * 128;

  f32x4 acc[2][8];
  #pragma unroll
  for (int cf = 0; cf < 8; ++cf) {
    float bv = bsum[colw + cf * 16 + lr];
    f32x4 z = {bv, bv, bv, bv};
    acc[0][cf] = z; acc[1][cf] = z;
  }

  #pragma unroll 1
  for (int kc = 0; kc < 16; ++kc) {
    const int kb = kc * 32 + g * 8;
    bf16x8 afr[2];
    #pragma unroll
    for (int ai = 0; ai < 2; ++ai) {
      const float* src = X + (size_t)(rowbase + ai * 16 + lr) * KDIM + kb;
      float4 lo = *reinterpret_cast<const float4*>(src);
      float4 hi = *reinterpret_cast<const float4*>(src + 4);
      bf16x8 a;
      a[0] = (short)f2bf(lo.x); a[1] = (short)f2bf(lo.y);
      a[2] = (short)f2bf(lo.z); a[3] = (short)f2bf(lo.w);
      a[4] = (short)f2bf(hi.x); a[5] = (short)f2bf(hi.y);
      a[6] = (short)f2bf(hi.z); a[7] = (short)f2bf(hi.w);
      afr[ai] = a;
    }
    #pragma unroll
    for (int cf = 0; cf < 8; ++cf) {
      const int cfg = (w & 3) * 8 + cf;
      uint4 braw = BW[(kc * 32 + cfg) * 64 + l];
      bf16x8 b = __builtin_bit_cast(bf16x8, braw);
      acc[0][cf] = mfma16(afr[0], b, acc[0][cf]);
      acc[1][cf] = mfma16(afr[1], b, acc[1][cf]);
    }
  }

  // natural-layout store: row = batch row, col = n  (scalar f32; phase 1 is ~1% of time)
  #pragma unroll
  for (int ai = 0; ai < 2; ++ai) {
    #pragma unroll
    for (int cf = 0; cf < 8; ++cf) {
      const int col = colw + cf * 16 + lr;
      #pragma unroll
      for (int r = 0; r < 4; ++r) {
        const int row = rowbase + ai * 16 + g * 4 + r;
        out[(size_t)row * HID + col] = acc[ai][cf][r];
      }
    }
  }
}

// Phase 2: sequential scan, ORIENTATION-SWAPPED: D[n_out][b] = sum_k W[n_out][k] h[b][k].
// 4 blocks x 256 threads (4 waves, 1 wave/SIMD -> 512-reg budget).
// Wave w owns m-frags mf = w*8..w*8+7  (n_out in [w*128, (w+1)*128)).
// LDS (163840 B):
//   [0,131072):      W_hh A-frags kf0-3, all 32 mf (frag f=kf*32+mf at f*1024, linear)
//   [131072,147456): h buf0: [16 b][512 n] bf16, rows XOR-swizzled by ((b&7)<<4)
//   [147456,163840): h buf1
// W_hh kf4..15 in 96 reg frags (384 VGPR/AGPR), fully static indexing.
// xp: global->reg f32x4 prefetch (natural layout). out: f32x4 stores.
__global__ __launch_bounds__(256, 1) void rnn_scan(
    const uint4* __restrict__ BW,   // W_hh frag-major bf16 (16384 frags)
    float* __restrict__ xo) {       // d_out: xp in (natural), h out (natural)
  extern __shared__ char smem[];
  const int tid = threadIdx.x, w = tid >> 6, l = tid & 63;
  const int g = l >> 4, lr = l & 15;
  const int bg = blockIdx.x;

  // stage W_hh kf0-3 (128 KB, linear)
  {
    uint4* lb = reinterpret_cast<uint4*>(smem);
    #pragma unroll
    for (int i = 0; i < 32; ++i) lb[i * 256 + tid] = BW[i * 256 + tid];
  }
  // zero h buf0
  {
    float* hz = reinterpret_cast<float*>(smem + 131072);
    #pragma unroll
    for (int i = 0; i < 16; ++i) hz[i * 256 + tid] = 0.f;
  }
  // register A-frags kf4..15 for this wave's 8 m-frags (static indices only)
  bf16x8 ar[12][8];
  #pragma unroll
  for (int kf = 0; kf < 12; ++kf)
    #pragma unroll
    for (int mf = 0; mf < 8; ++mf)
      ar[kf][mf] = __builtin_bit_cast(bf16x8,
          BW[((kf + 4) * 32 + (w * 8 + mf)) * 64 + l]);
  __syncthreads();

  // per-lane constants
  const int hswz = (lr & 7) << 4;
  const int bpre = lr * 1024 + g * 16;          // h B-read: +kf*64, ^hswz, +hbase
  const int apre = (w * 8) * 1024 + l * 16;     // W A-read: +(kf*32+mf)*1024
  const int wpre = lr * 1024 + (w * 8) * 32 + g * 8;  // h write: +mf*32, ^hswz, +hbase
  float* xrow0 = xo + ((size_t)bg * 16 + lr) * HID + (size_t)(w * 8) * 16 + g * 4;

  // prologue: xp(0) -> regs
  f32x4 xv[8];
  #pragma unroll
  for (int mf = 0; mf < 8; ++mf)
    xv[mf] = *reinterpret_cast<const f32x4*>(xrow0 + mf * 16);

#define SCAN_STEP(S, RD, WR)                                                      \
  {                                                                               \
    const int s = (S);                                                            \
    f32x4 acc[8];                                                                 \
    _Pragma("unroll")                                                             \
    for (int mf = 0; mf < 8; ++mf) acc[mf] = xv[mf];                              \
    { /* prefetch xp(s+1) -> xv (consumed next step; clamp harmless at tail) */   \
      const float* xn = xrow0 + (size_t)(s + 1 < SEQ ? s + 1 : s) * (64 * HID);   \
      _Pragma("unroll")                                                           \
      for (int mf = 0; mf < 8; ++mf)                                              \
        xv[mf] = *reinterpret_cast<const f32x4*>(xn + mf * 16);                   \
    }                                                                             \
    _Pragma("unroll")                                                             \
    for (int kf = 0; kf < 4; ++kf) {                                              \
      bf16x8 hb = *reinterpret_cast<const bf16x8*>(                               \
          smem + 131072 + (RD) + ((bpre + kf * 64) ^ hswz));                      \
      const char* ab = smem + ((kf * 32) << 10) + apre;                           \
      acc[0] = mfma16(*reinterpret_cast<const bf16x8*>(ab + 0 * 1024), hb, acc[0]); \
      acc[1] = mfma16(*reinterpret_cast<const bf16x8*>(ab + 1 * 1024), hb, acc[1]); \
      acc[2] = mfma16(*reinterpret_cast<const bf16x8*>(ab + 2 * 1024), hb, acc[2]); \
      acc[3] = mfma16(*reinterpret_cast<const bf16x8*>(ab + 3 * 1024), hb, acc[3]); \
      acc[4] = mfma16(*reinterpret_cast<const bf16x8*>(ab + 4 * 1024), hb, acc[4]); \
      acc[5] = mfma16(*reinterpret_cast<const bf16x8*>(ab + 5 * 1024), hb, acc[5]); \
      acc[6] = mfma16(*reinterpret_cast<const bf16x8*>(ab + 6 * 1024), hb, acc[6]); \
      acc[7] = mfma16(*reinterpret_cast<const bf16x8*>(ab + 7 * 1024), hb, acc[7]); \
    }                                                                             \
    _Pragma("unroll")                                                             \
    for (int kf = 0; kf < 12; ++kf) {                                             \
      bf16x8 hb = *reinterpret_cast<const bf16x8*>(                               \
          smem + 131072 + (RD) + ((bpre + (kf + 4) * 64) ^ hswz));                \
      acc[0] = mfma16(ar[kf][0], hb, acc[0]);                                     \
      acc[1] = mfma16(ar[kf][1], hb, acc[1]);                                     \
      acc[2] = mfma16(ar[kf][2], hb, acc[2]);                                     \
      acc[3] = mfma16(ar[kf][3], hb, acc[3]);                                     \
      acc[4] = mfma16(ar[kf][4], hb, acc[4]);                                     \
      acc[5] = mfma16(ar[kf][5], hb, acc[5]);                                     \
      acc[6] = mfma16(ar[kf][6], hb, acc[6]);                                     \
      acc[7] = mfma16(ar[kf][7], hb, acc[7]);                                     \
    }                                                                             \
    /* epilogue: tanh, pack 4xbf16 -> ds_write_b64 h[WR], f32x4 -> out */         \
    float* orow = xrow0 + (size_t)s * (64 * HID);                                 \
    _Pragma("unroll")                                                             \
    for (int mf = 0; mf < 8; ++mf) {                                              \
      f32x4 hv;                                                                   \
      _Pragma("unroll")                                                           \
      for (int r = 0; r < 4; ++r) {                                               \
        const float pre = acc[mf][r];                                             \
        hv[r] = 1.0f - 2.0f * __builtin_amdgcn_rcpf(1.0f + __expf(2.0f * pre));   \
      }                                                                           \
      *reinterpret_cast<f32x4*>(orow + mf * 16) = hv;                             \
      uint2 hp;                                                                   \
      hp.x = (unsigned)f2bf(hv[0]) | ((unsigned)f2bf(hv[1]) << 16);               \
      hp.y = (unsigned)f2bf(hv[2]) | ((unsigned)f2bf(hv[3]) << 16);               \
      *reinterpret_cast<uint2*>(                                                  \
          smem + 131072 + (WR) + ((wpre + mf * 32) ^ hswz)) = hp;                 \
    }                                                                             \
    asm volatile("s_waitcnt lgkmcnt(0)" ::: "memory");                            \
    __builtin_amdgcn_s_barrier();                                                 \
    __builtin_amdgcn_sched_barrier(0);                                            \
  }

  #pragma unroll 1
  for (int s2 = 0; s2 < SEQ; s2 += 2) {
    SCAN_STEP(s2,     0,     16384)
    SCAN_STEP(s2 + 1, 16384, 0)
  }
#undef SCAN_STEP
}

extern "C" void kernel_launch(void* const* d_in, const int* in_sizes, int n_in,
                              void* d_out, int out_size, void* d_ws, size_t ws_size,
                              hipStream_t stream) {
  (void)in_sizes; (void)n_in; (void)out_size;
  const float* X   = (const float*)d_in[0];
  const float* Wih = (const float*)d_in[1];
  const float* Whh = (const float*)d_in[2];
  const float* bih = (const float*)d_in[3];
  const float* bhh = (const float*)d_in[4];
  float* out = (float*)d_out;

  unsigned short* wihf = (unsigned short*)d_ws;              // 512 KB
  unsigned short* whhf = wihf + 262144;                      // 512 KB
  float* bsum = (float*)(whhf + 262144);                     // 2 KB
  if (ws_size < (size_t)(2 * 524288 + 2048)) return;

  prep_wfrag<<<1024, 256, 0, stream>>>(Wih, wihf);
  prep_wfrag<<<1024, 256, 0, stream>>>(Whh, whhf);
  prep_bsum<<<1, 512, 0, stream>>>(bih, bhh, bsum);

  rnn_xproj<<<2048, 512, 0, stream>>>(X, (const uint4*)wihf, bsum, out);

  hipFuncSetAttribute(reinterpret_cast<const void*>(rnn_scan),
                      hipFuncAttributeMaxDynamicSharedMemorySize, 163840);
  rnn_scan<<<4, 256, 163840, stream>>>((const uint4*)whhf, out);
}

// Round 5
// 5938.571 us; speedup vs baseline: 1.8319x; 1.0285x over previous
//
#include <hip/hip_runtime.h>
#include <hip/hip_bf16.h>

#define SEQ   2048
#define NBATCH 64
#define HID   512
#define KDIM  512

typedef float f32x4  __attribute__((ext_vector_type(4)));
typedef short bf16x8 __attribute__((ext_vector_type(8)));

__device__ __forceinline__ unsigned short f2bf(float f) {
  union { float f; unsigned int u; } v; v.f = f;
  unsigned int r = v.u + 0x7FFFu + ((v.u >> 16) & 1u);
  return (unsigned short)(r >> 16);
}

__device__ __forceinline__ f32x4 mfma16(bf16x8 a, bf16x8 b, f32x4 c) {
  return __builtin_amdgcn_mfma_f32_16x16x32_bf16(a, b, c, 0, 0, 0);
}

// Repack W [H=512 rows n][K=512 cols k] (row-major fp32) into MFMA-fragment-major bf16:
// element index = ((kf*32 + cfg)*64 + lane)*8 + e  with n = cfg*16 + (lane&15),
// k = kf*32 + (lane>>4)*8 + e.  Used as B-frag (phase 1) and A-frag (scan).
__global__ void prep_wfrag(const float* __restrict__ W, unsigned short* __restrict__ dst) {
  int tid = blockIdx.x * blockDim.x + threadIdx.x;   // 0 .. 262143
  int e   = tid & 7;
  int l   = (tid >> 3) & 63;
  int cfg = (tid >> 9) & 31;
  int kf  = tid >> 14;
  int n = cfg * 16 + (l & 15);
  int k = kf * 32 + (l >> 4) * 8 + e;
  dst[tid] = f2bf(W[n * KDIM + k]);
}

__global__ void prep_bsum(const float* __restrict__ a, const float* __restrict__ b,
                          float* __restrict__ out) {
  int j = threadIdx.x;
  if (j < HID) out[j] = a[j] + b[j];
}

// Phase 1: xp = X * W_ih^T + (b_ih + b_hh), written to d_out in NATURAL layout
// [s*64+b][n] fp32 (the scan reads it as f32x4 per (b, n-quad)).
__global__ __launch_bounds__(512) void rnn_xproj(
    const float* __restrict__ X,      // [131072, 512] fp32
    const uint4* __restrict__ BW,     // W_ih frag-major bf16
    const float* __restrict__ bsum,   // [512]
    float* __restrict__ out) {        // [131072, 512] fp32 (xp)
  const int tid = threadIdx.x, w = tid >> 6, l = tid & 63;
  const int g = l >> 4, lr = l & 15;
  const int rowbase = blockIdx.x * 64 + (w >> 2) * 32;
  const int colw = (w & 3) * 128;

  f32x4 acc[2][8];
  #pragma unroll
  for (int cf = 0; cf < 8; ++cf) {
    float bv = bsum[colw + cf * 16 + lr];
    f32x4 z = {bv, bv, bv, bv};
    acc[0][cf] = z; acc[1][cf] = z;
  }

  #pragma unroll 1
  for (int kc = 0; kc < 16; ++kc) {
    const int kb = kc * 32 + g * 8;
    bf16x8 afr[2];
    #pragma unroll
    for (int ai = 0; ai < 2; ++ai) {
      const float* src = X + (size_t)(rowbase + ai * 16 + lr) * KDIM + kb;
      float4 lo = *reinterpret_cast<const float4*>(src);
      float4 hi = *reinterpret_cast<const float4*>(src + 4);
      bf16x8 a;
      a[0] = (short)f2bf(lo.x); a[1] = (short)f2bf(lo.y);
      a[2] = (short)f2bf(lo.z); a[3] = (short)f2bf(lo.w);
      a[4] = (short)f2bf(hi.x); a[5] = (short)f2bf(hi.y);
      a[6] = (short)f2bf(hi.z); a[7] = (short)f2bf(hi.w);
      afr[ai] = a;
    }
    #pragma unroll
    for (int cf = 0; cf < 8; ++cf) {
      const int cfg = (w & 3) * 8 + cf;
      uint4 braw = BW[(kc * 32 + cfg) * 64 + l];
      bf16x8 b = __builtin_bit_cast(bf16x8, braw);
      acc[0][cf] = mfma16(afr[0], b, acc[0][cf]);
      acc[1][cf] = mfma16(afr[1], b, acc[1][cf]);
    }
  }

  // natural-layout store
  #pragma unroll
  for (int ai = 0; ai < 2; ++ai) {
    #pragma unroll
    for (int cf = 0; cf < 8; ++cf) {
      const int col = colw + cf * 16 + lr;
      #pragma unroll
      for (int r = 0; r < 4; ++r) {
        const int row = rowbase + ai * 16 + g * 4 + r;
        out[(size_t)row * HID + col] = acc[ai][cf][r];
      }
    }
  }
}

// Phase 2: sequential scan, orientation-swapped: D[n_out][b] = sum_k W[n_out][k] h[b][k].
// 4 blocks x 512 threads (8 waves, 2 waves/SIMD -> full MFMA issue rate; 256-reg budget).
// Wave w owns m-frags mf = w*4..w*4+3  (n_out in [w*64, (w+1)*64)).
// LDS (163840 B):
//   [0,131072):      W_hh A-frags kf0-3, all 32 mf (frag f=kf*32+mf at f*1024, linear)
//   [131072,147456): h buf0: [16 b][512 n] bf16, rows XOR-swizzled by ((b&7)<<4)
//   [147456,163840): h buf1
// W_hh kf4..15 in 48 reg frags (192 regs), fully static indexing.
// xp: global->reg f32x4 prefetch (natural layout). out: f32x4 stores.
__global__ __launch_bounds__(512, 2) void rnn_scan(
    const uint4* __restrict__ BW,   // W_hh frag-major bf16 (16384 frags)
    float* __restrict__ xo) {       // d_out: xp in (natural), h out (natural)
  extern __shared__ char smem[];
  const int tid = threadIdx.x, w = tid >> 6, l = tid & 63;
  const int g = l >> 4, lr = l & 15;
  const int bg = blockIdx.x;

  // stage W_hh kf0-3 (128 KB, linear)
  {
    uint4* lb = reinterpret_cast<uint4*>(smem);
    #pragma unroll
    for (int i = 0; i < 16; ++i) lb[i * 512 + tid] = BW[i * 512 + tid];
  }
  // zero h buf0
  {
    float* hz = reinterpret_cast<float*>(smem + 131072);
    #pragma unroll
    for (int i = 0; i < 8; ++i) hz[i * 512 + tid] = 0.f;
  }
  // register A-frags kf4..15 for this wave's 4 m-frags (static indices only)
  bf16x8 ar[12][4];
  #pragma unroll
  for (int kf = 0; kf < 12; ++kf)
    #pragma unroll
    for (int mf = 0; mf < 4; ++mf)
      ar[kf][mf] = __builtin_bit_cast(bf16x8,
          BW[((kf + 4) * 32 + (w * 4 + mf)) * 64 + l]);
  __syncthreads();

  // per-lane constants
  const int hswz = (lr & 7) << 4;
  const int bpre = lr * 1024 + g * 16;          // h B-read: +kf*64, ^hswz, +hbase
  const int apre = (w * 4) * 1024 + l * 16;     // W A-read: +kf*32*1024 (+mf*1024)
  const int wpre = lr * 1024 + (w * 4) * 32 + g * 8;  // h write: +mf*32, ^hswz, +hbase
  float* xrow0 = xo + ((size_t)bg * 16 + lr) * HID + (size_t)(w * 4) * 16 + g * 4;

  // prologue: xp(0) -> regs
  f32x4 xv[4];
  #pragma unroll
  for (int mf = 0; mf < 4; ++mf)
    xv[mf] = *reinterpret_cast<const f32x4*>(xrow0 + mf * 16);

#define SCAN_STEP(S, RD, WR)                                                      \
  {                                                                               \
    const int s = (S);                                                            \
    f32x4 acc[4];                                                                 \
    _Pragma("unroll")                                                             \
    for (int mf = 0; mf < 4; ++mf) acc[mf] = xv[mf];                              \
    { /* prefetch xp(s+1) -> xv (consumed next step; clamp harmless at tail) */   \
      const float* xn = xrow0 + (size_t)(s + 1 < SEQ ? s + 1 : s) * (64 * HID);   \
      _Pragma("unroll")                                                           \
      for (int mf = 0; mf < 4; ++mf)                                              \
        xv[mf] = *reinterpret_cast<const f32x4*>(xn + mf * 16);                   \
    }                                                                             \
    _Pragma("unroll")                                                             \
    for (int kf = 0; kf < 4; ++kf) {                                              \
      bf16x8 hb = *reinterpret_cast<const bf16x8*>(                               \
          smem + 131072 + (RD) + ((bpre + kf * 64) ^ hswz));                      \
      const char* ab = smem + ((kf * 32) << 10) + apre;                           \
      acc[0] = mfma16(*reinterpret_cast<const bf16x8*>(ab + 0 * 1024), hb, acc[0]); \
      acc[1] = mfma16(*reinterpret_cast<const bf16x8*>(ab + 1 * 1024), hb, acc[1]); \
      acc[2] = mfma16(*reinterpret_cast<const bf16x8*>(ab + 2 * 1024), hb, acc[2]); \
      acc[3] = mfma16(*reinterpret_cast<const bf16x8*>(ab + 3 * 1024), hb, acc[3]); \
    }                                                                             \
    _Pragma("unroll")                                                             \
    for (int kf = 0; kf < 12; ++kf) {                                             \
      bf16x8 hb = *reinterpret_cast<const bf16x8*>(                               \
          smem + 131072 + (RD) + ((bpre + (kf + 4) * 64) ^ hswz));                \
      acc[0] = mfma16(ar[kf][0], hb, acc[0]);                                     \
      acc[1] = mfma16(ar[kf][1], hb, acc[1]);                                     \
      acc[2] = mfma16(ar[kf][2], hb, acc[2]);                                     \
      acc[3] = mfma16(ar[kf][3], hb, acc[3]);                                     \
    }                                                                             \
    /* epilogue: tanh, pack 4xbf16 -> 8B h write, f32x4 -> out */                 \
    float* orow = xrow0 + (size_t)s * (64 * HID);                                 \
    _Pragma("unroll")                                                             \
    for (int mf = 0; mf < 4; ++mf) {                                              \
      f32x4 hv;                                                                   \
      _Pragma("unroll")                                                           \
      for (int r = 0; r < 4; ++r) {                                               \
        const float pre = acc[mf][r];                                             \
        hv[r] = 1.0f - 2.0f * __builtin_amdgcn_rcpf(1.0f + __expf(2.0f * pre));   \
      }                                                                           \
      *reinterpret_cast<f32x4*>(orow + mf * 16) = hv;                             \
      uint2 hp;                                                                   \
      hp.x = (unsigned)f2bf(hv[0]) | ((unsigned)f2bf(hv[1]) << 16);               \
      hp.y = (unsigned)f2bf(hv[2]) | ((unsigned)f2bf(hv[3]) << 16);               \
      *reinterpret_cast<uint2*>(                                                  \
          smem + 131072 + (WR) + ((wpre + mf * 32) ^ hswz)) = hp;                 \
    }                                                                             \
    asm volatile("s_waitcnt lgkmcnt(0)" ::: "memory");                            \
    __builtin_amdgcn_s_barrier();                                                 \
    __builtin_amdgcn_sched_barrier(0);                                            \
  }

  #pragma unroll 1
  for (int s2 = 0; s2 < SEQ; s2 += 2) {
    SCAN_STEP(s2,     0,     16384)
    SCAN_STEP(s2 + 1, 16384, 0)
  }
#undef SCAN_STEP
}

extern "C" void kernel_launch(void* const* d_in, const int* in_sizes, int n_in,
                              void* d_out, int out_size, void* d_ws, size_t ws_size,
                              hipStream_t stream) {
  (void)in_sizes; (void)n_in; (void)out_size;
  const float* X   = (const float*)d_in[0];
  const float* Wih = (const float*)d_in[1];
  const float* Whh = (const float*)d_in[2];
  const float* bih = (const float*)d_in[3];
  const float* bhh = (const float*)d_in[4];
  float* out = (float*)d_out;

  unsigned short* wihf = (unsigned short*)d_ws;              // 512 KB
  unsigned short* whhf = wihf + 262144;                      // 512 KB
  float* bsum = (float*)(whhf + 262144);                     // 2 KB
  if (ws_size < (size_t)(2 * 524288 + 2048)) return;

  prep_wfrag<<<1024, 256, 0, stream>>>(Wih, wihf);
  prep_wfrag<<<1024, 256, 0, stream>>>(Whh, whhf);
  prep_bsum<<<1, 512, 0, stream>>>(bih, bhh, bsum);

  rnn_xproj<<<2048, 512, 0, stream>>>(X, (const uint4*)wihf, bsum, out);

  hipFuncSetAttribute(reinterpret_cast<const void*>(rnn_scan),
                      hipFuncAttributeMaxDynamicSharedMemorySize, 163840);
  rnn_scan<<<4, 512, 163840, stream>>>((const uint4*)whhf, out);
}